// Round 2
// baseline (540.829 us; speedup 1.0000x reference)
//
#include <hip/hip_runtime.h>

// JBF block, pipelined: 512 persistent 1-wave blocks, each streams 16 chunks
// of 64 voxels. LDS A/B (32 KB each) staged via global_load_lds (width 16),
// manual s_waitcnt vmcnt(N) pipelining (in-order retirement, m135 semantics).
//
// Per-chunk steady state:
//   wait vmcnt(32)      -> A = dom(c) ready     [gui(c) 32 in flight]
//   dk = conv(A)
//   issue dom(c+1)->A   [gui(c)=32 + dom(c+1)=32 outstanding]
//   wait vmcnt(32)      -> B = gui(c) ready     [dom(c+1) 32 in flight]
//   x prefetch, rk = conv(B), epilogue, store
//   issue gui(c+1)->B
// => every wave keeps >=32 KB of loads in flight at all times.

#define REC   125      // floats per record
#define VPB   64       // voxels per chunk == wave size
#define NC    16       // chunks per block
#define BUF_F 8000     // floats per LDS buffer (64 records, 32000 B)

__device__ __forceinline__ void dma_buf(const float* gsrc, float* lds, int lane) {
    // 31 x 16B/lane + 1 x 4B/lane = exactly 8000 floats, all 16B-aligned
    // (chunk base = ch*32000 B, k*1024 B steps). LDS dest: uniform base +
    // lane*size (HW rule), matches contiguous layout.
#pragma unroll
    for (int k = 0; k < 31; ++k) {
        __builtin_amdgcn_global_load_lds(
            (const __attribute__((address_space(1))) void*)(gsrc + k * 256 + lane * 4),
            (__attribute__((address_space(3))) void*)(lds + k * 256),
            16, 0, 0);
    }
    __builtin_amdgcn_global_load_lds(
        (const __attribute__((address_space(1))) void*)(gsrc + 31 * 256 + lane),
        (__attribute__((address_space(3))) void*)(lds + 31 * 256),
        4, 0, 0);
}

__device__ __forceinline__ void conv555_333(const float* __restrict__ rec,
                                            const float* __restrict__ wt,
                                            float* __restrict__ acc) {
#pragma unroll
    for (int z = 0; z < 5; ++z)
#pragma unroll
        for (int r = 0; r < 5; ++r)
#pragma unroll
            for (int c = 0; c < 5; ++c) {
                const float v = rec[z * 25 + r * 5 + c];
#pragma unroll
                for (int i = 0; i < 3; ++i) {
                    const int a = z - i; if (a < 0 || a > 2) continue;
#pragma unroll
                    for (int j = 0; j < 3; ++j) {
                        const int b = r - j; if (b < 0 || b > 2) continue;
#pragma unroll
                        for (int l = 0; l < 3; ++l) {
                            const int cc = c - l; if (cc < 0 || cc > 2) continue;
                            acc[(i * 3 + j) * 3 + l] =
                                fmaf(v, wt[(a * 3 + b) * 3 + cc],
                                     acc[(i * 3 + j) * 3 + l]);
                        }
                    }
                }
            }
}

__global__ __launch_bounds__(64) void jbf_kernel(
    const float* __restrict__ x,      // [2,1,18,128,128]
    const float* __restrict__ dom,    // [M,125]
    const float* __restrict__ gui,    // [M,125]
    const float* __restrict__ dom_w,  // [27]
    const float* __restrict__ dom_b,  // [1]
    const float* __restrict__ rng_w,  // [27]
    const float* __restrict__ rng_b,  // [1]
    float* __restrict__ out)          // [M]
{
    __shared__ __align__(16) float A[BUF_F];
    __shared__ __align__(16) float B[BUF_F];
    const int lane = threadIdx.x;
    const int ch0  = blockIdx.x * NC;

    // uniform conv weights -> SGPRs
    float wd[27], wr[27];
#pragma unroll
    for (int i = 0; i < 27; ++i) { wd[i] = dom_w[i]; wr[i] = rng_w[i]; }
    const float bd = dom_b[0], br = rng_b[0];

    // prologue: fill pipeline
    dma_buf(dom + (size_t)ch0 * BUF_F, A, lane);
    dma_buf(gui + (size_t)ch0 * BUF_F, B, lane);

#pragma clang loop unroll(disable)
    for (int c = 0; c < NC; ++c) {
        const int ch = ch0 + c;
        const int m  = ch * VPB + lane;

        // ---- A = dom(ch) ready; gui(ch) (newest 32) still in flight ----
        asm volatile("s_waitcnt vmcnt(32)" ::: "memory");

        float dkv[27];
#pragma unroll
        for (int i = 0; i < 27; ++i) dkv[i] = 0.f;
        conv555_333(A + lane * REC, wd, dkv);

        if (c + 1 < NC)
            dma_buf(dom + (size_t)(ch + 1) * BUF_F, A, lane);

        // ---- B = gui(ch) ready; dom(ch+1) (newest 32) still in flight ----
        if (c + 1 < NC) { asm volatile("s_waitcnt vmcnt(32)" ::: "memory"); }
        else            { asm volatile("s_waitcnt vmcnt(0)"  ::: "memory"); }

        // x-neighborhood prefetch (L2/L3-resident; issued after the wait so
        // its compiler-managed waits never force-drain the DMA pipeline
        // beyond dom(ch+1), which has the whole rk phase to land)
        const int w_ = m & 127;
        const int h_ = (m >> 7) & 127;
        const int dz = (m >> 14) & 15;
        const int b_ = m >> 18;
        float xv[27];
#pragma unroll
        for (int i = 0; i < 3; ++i) {
            const int zz = b_ * 18 + dz + i;
#pragma unroll
            for (int j = 0; j < 3; ++j) {
                const int hh = h_ - 1 + j;
                const bool okh = (unsigned)hh < 128u;
#pragma unroll
                for (int l = 0; l < 3; ++l) {
                    const int ww = w_ - 1 + l;
                    const bool ok = okh && ((unsigned)ww < 128u);
                    xv[(i * 3 + j) * 3 + l] =
                        ok ? x[((size_t)zz * 128 + hh) * 128 + ww] : 0.f;
                }
            }
        }

        float rkv[27];
#pragma unroll
        for (int i = 0; i < 27; ++i) rkv[i] = 0.f;
        conv555_333(B + lane * REC, wr, rkv);

        float num = 0.f, den = 0.f;
#pragma unroll
        for (int k = 0; k < 27; ++k) {
            const float wv = fmaxf(dkv[k] + bd, 0.f) *
                             fmaxf(rkv[k] + br, 0.f) + 1e-10f;
            den += wv;
            num = fmaf(wv, xv[k], num);
        }
        out[m] = num / den;

        if (c + 1 < NC)
            dma_buf(gui + (size_t)(ch + 1) * BUF_F, B, lane);
    }
}

extern "C" void kernel_launch(void* const* d_in, const int* in_sizes, int n_in,
                              void* d_out, int out_size, void* d_ws, size_t ws_size,
                              hipStream_t stream) {
    const float* x     = (const float*)d_in[0];
    const float* dom   = (const float*)d_in[1];
    const float* gui   = (const float*)d_in[2];
    const float* dom_w = (const float*)d_in[3];
    const float* dom_b = (const float*)d_in[4];
    const float* rng_w = (const float*)d_in[5];
    const float* rng_b = (const float*)d_in[6];
    float* outp = (float*)d_out;

    const int M = in_sizes[1] / REC;          // 524288
    const int grid = M / (VPB * NC);          // 512 blocks (2/CU, single round)
    jbf_kernel<<<grid, VPB, 0, stream>>>(x, dom, gui, dom_w, dom_b,
                                         rng_w, rng_b, outp);
}